// Round 11
// baseline (551.011 us; speedup 1.0000x reference)
//
#include <hip/hip_runtime.h>
#include <stdint.h>

#define NT 8192      // tokens
#define DM 1024      // d_model
#define DF 2048      // d_ff
#define RT_BLOCKS 256

typedef __attribute__((ext_vector_type(8))) short short8;
typedef __attribute__((ext_vector_type(4))) float f32x4;
typedef unsigned short us;

__device__ __forceinline__ us f2bf(float f) {
  uint32_t x = __float_as_uint(f);
  return (us)((x + 0x7fffu + ((x >> 16) & 1u)) >> 16);
}
__device__ __forceinline__ float bf2f(us v) {
  return __uint_as_float(((uint32_t)v) << 16);
}

__device__ __forceinline__ void gload16(const void* g, void* l) {
  __builtin_amdgcn_global_load_lds(
      (const __attribute__((address_space(1))) uint32_t*)g,
      (__attribute__((address_space(3))) uint32_t*)l, 16, 0, 0);
}

// ---------------- weight converts ----------------
// W13 pairing layout: W1 row f -> n = 32*(f>>4) + (f&15); W3 row f -> +16.
__global__ void k_cvtw(const float4* __restrict__ w1, const float4* __restrict__ w3,
                       const float4* __restrict__ w2,
                       ushort4* __restrict__ w13, ushort4* __restrict__ w2bf) {
  int s = blockIdx.y;
  const float4* src = (s == 0) ? w1 : (s == 1) ? w3 : w2;
  int n4 = 8 * DF * DM / 4;
  int i = blockIdx.x * blockDim.x + threadIdx.x;
  int st = gridDim.x * blockDim.x;
  for (; i < n4; i += st) {
    float4 v = src[i];
    ushort4 o;
    o.x = f2bf(v.x); o.y = f2bf(v.y); o.z = f2bf(v.z); o.w = f2bf(v.w);
    if (s == 2) {
      w2bf[i] = o;
    } else {
      int e = i >> 19;
      int rem = i & ((1 << 19) - 1);
      int f = rem >> 8;
      int k4 = rem & 255;
      int n = 32 * (f >> 4) + 16 * s + (f & 15);
      w13[((size_t)e << 20) + (size_t)n * 256 + k4] = o;
    }
  }
}

// ---------------- router ----------------
__global__ void k_router(const float* __restrict__ x, const float* __restrict__ wr,
                         int* cntb, int* cnt1, float* imp, float* z2,
                         int* epack, float2* gts, us* __restrict__ xbf) {
  int lane = threadIdx.x & 63;
  int wid = threadIdx.x >> 6;
  const float4* w4 = (const float4*)wr;

  float imp_acc[8] = {0.f, 0.f, 0.f, 0.f, 0.f, 0.f, 0.f, 0.f};
  float z2_acc = 0.f;
  int cb_acc[8] = {0, 0, 0, 0, 0, 0, 0, 0};
  int c1_acc[8] = {0, 0, 0, 0, 0, 0, 0, 0};

  for (int t = blockIdx.x * 4 + wid; t < NT; t += RT_BLOCKS * 4) {
    const float4* x4 = (const float4*)(x + (size_t)t * DM);
    ushort4* xb4 = (ushort4*)(xbf + (size_t)t * DM);
    float4 xv[4];
    #pragma unroll
    for (int j = 0; j < 4; ++j) {
      xv[j] = x4[lane + 64 * j];
      ushort4 o;
      o.x = f2bf(xv[j].x); o.y = f2bf(xv[j].y); o.z = f2bf(xv[j].z); o.w = f2bf(xv[j].w);
      xb4[lane + 64 * j] = o;
    }
    float p[8];
    #pragma unroll
    for (int e = 0; e < 8; ++e) p[e] = 0.f;
    #pragma unroll
    for (int j = 0; j < 4; ++j) {
      #pragma unroll
      for (int e = 0; e < 8; ++e) {
        float4 wv = w4[e * 256 + lane + 64 * j];
        p[e] += xv[j].x * wv.x + xv[j].y * wv.y + xv[j].z * wv.z + xv[j].w * wv.w;
      }
    }
    #pragma unroll
    for (int off = 32; off > 0; off >>= 1) {
      #pragma unroll
      for (int e = 0; e < 8; ++e) p[e] += __shfl_down(p[e], off);
    }
    if (lane == 0) {
      float m = p[0];
      #pragma unroll
      for (int e = 1; e < 8; ++e) m = fmaxf(m, p[e]);
      float pr[8], sum = 0.f;
      #pragma unroll
      for (int e = 0; e < 8; ++e) { pr[e] = expf(p[e] - m); sum += pr[e]; }
      float inv = 1.f / sum;
      #pragma unroll
      for (int e = 0; e < 8; ++e) pr[e] *= inv;
      float z = m + logf(sum);
      int e0 = 0; float b0 = p[0];
      #pragma unroll
      for (int e = 1; e < 8; ++e) { if (p[e] > b0) { b0 = p[e]; e0 = e; } }
      int e1 = -1; float b1 = -1e30f;
      #pragma unroll
      for (int e = 0; e < 8; ++e) { if (e != e0 && p[e] > b1) { b1 = p[e]; e1 = e; } }
      float p0 = 0.f, p1 = 0.f;
      #pragma unroll
      for (int e = 0; e < 8; ++e) {
        p0 = (e == e0) ? pr[e] : p0;
        p1 = (e == e1) ? pr[e] : p1;
      }
      float gs = p0 + p1 + 1e-9f;
      epack[t] = e0 | (e1 << 16);
      gts[t] = make_float2(p0 / gs, p1 / gs);
      z2_acc += z * z;
      #pragma unroll
      for (int e = 0; e < 8; ++e) {
        imp_acc[e] += pr[e];
        cb_acc[e] += (e == e0) + (e == e1);
        c1_acc[e] += (e == e0);
      }
    }
  }

  __shared__ float simp[4][8];
  __shared__ float sz2[4];
  __shared__ int scb[4][8];
  __shared__ int sc1[4][8];
  if (lane == 0) {
    #pragma unroll
    for (int e = 0; e < 8; ++e) { simp[wid][e] = imp_acc[e]; scb[wid][e] = cb_acc[e]; sc1[wid][e] = c1_acc[e]; }
    sz2[wid] = z2_acc;
  }
  __syncthreads();
  int tid = threadIdx.x;
  if (tid < 8) {
    float ss = simp[0][tid] + simp[1][tid] + simp[2][tid] + simp[3][tid];
    int b = scb[0][tid] + scb[1][tid] + scb[2][tid] + scb[3][tid];
    int o = sc1[0][tid] + sc1[1][tid] + sc1[2][tid] + sc1[3][tid];
    atomicAdd(&imp[tid], ss);
    atomicAdd(&cntb[tid], b);
    atomicAdd(&cnt1[tid], o);
  } else if (tid == 8) {
    atomicAdd(z2, sz2[0] + sz2[1] + sz2[2] + sz2[3]);
  }
}

// ---------------- offsets + scalar losses ----------------
__global__ void k_finalize(const int* cntb, const int* cnt1, const float* imp,
                           const float* z2, int* offs, float* otail) {
  if (threadIdx.x == 0 && blockIdx.x == 0) {
    int o = 0;
    for (int e = 0; e < 8; ++e) { offs[e] = o; o += cntb[e]; }
    otail[0] = 1e-3f * z2[0] / (float)NT;
    float aux = 0.f;
    for (int e = 0; e < 8; ++e)
      aux += (imp[e] / (float)NT) * ((float)cnt1[e] / (float)NT);
    otail[1] = aux * 8.f;
  }
}

// ---------------- deterministic stable scatter ----------------
__global__ void k_scatter(const int* __restrict__ epack, const float2* __restrict__ gts,
                          const int* __restrict__ offs,
                          int* __restrict__ btok, int* __restrict__ pos) {
  int e = blockIdx.x;
  int lane = threadIdx.x;
  int base = offs[e];
  int run = 0;
  for (int j0 = 0; j0 < 2 * NT; j0 += 64) {
    int j = j0 + lane;
    int t = j >> 1;
    int ep = epack[t];
    int sel = (j & 1) ? (ep >> 16) : (ep & 0xffff);
    bool f = (sel == e);
    unsigned long long m = __ballot(f);
    int rank = __popcll(m & ((1ull << lane) - 1ull));
    if (f) {
      int slot = base + run + rank;
      btok[slot] = t;
      pos[j] = slot;
    }
    run += __popcll(m);
  }
}

// ============ corrected phase: reads -> stage -> [vmcnt] -> barrier -> MFMA ============
// vmcnt(4) is placed BEFORE the barrier (phases 1 & 3): the NEXT phase's
// pre-barrier ds_reads are then protected by this phase's barrier.
// Ring readiness: ph1's vmcnt drains sl1's staging (t-1 ph2/ph3 = oldest 4);
// ph3's drains next tile's sl0. WAR: a slot's restage is >=2 barriers after
// its last ds_read was consumed.
#define FFN_PHASE(slot, mi0, DOB, STAGE_STMT, VM)                               \
  if (DOB) {                                                                    \
    _Pragma("unroll")                                                           \
    for (int ni = 0; ni < 4; ++ni)                                              \
      b[ni] = *(const short8*)&Bs[slot][boff + ni * 512];                       \
  }                                                                             \
  _Pragma("unroll")                                                             \
  for (int mi = 0; mi < 4; ++mi)                                                \
    a[mi] = *(const short8*)&As[slot][aoff + (mi0 + mi) * 512];                 \
  STAGE_STMT;                                                                   \
  if (VM) asm volatile("s_waitcnt vmcnt(4)" ::: "memory");                      \
  __builtin_amdgcn_s_barrier();                                                 \
  __builtin_amdgcn_sched_barrier(0);                                            \
  __builtin_amdgcn_s_setprio(1);                                                \
  _Pragma("unroll")                                                             \
  for (int mi = 0; mi < 4; ++mi) {                                              \
    _Pragma("unroll")                                                           \
    for (int ni = 0; ni < 4; ++ni)                                              \
      acc[mi0 + mi][ni] =                                                       \
          __builtin_amdgcn_mfma_f32_16x16x32_bf16(a[mi], b[ni],                 \
                                                  acc[mi0 + mi][ni], 0, 0, 0);  \
  }                                                                             \
  __builtin_amdgcn_s_setprio(0);

// ---------------- FFN pass 1: Hg = silu(Xg*W1^T)*(Xg*W3^T) ----------------
__global__ __launch_bounds__(512, 2) void k_ffn1(
    const us* __restrict__ xb, const us* __restrict__ w13,
    const int* __restrict__ offs, const int* __restrict__ cnts,
    const int* __restrict__ btok, us* __restrict__ hg) {
  int e = blockIdx.z;
  int cnt = cnts[e];
  int m0 = blockIdx.y * 256;
  if (m0 >= cnt) return;
  int n0 = blockIdx.x * 256;
  int off = offs[e];
  __shared__ __align__(16) short As[4][8192];
  __shared__ __align__(16) short Bs[4][8192];
  __shared__ int tok[256];
  int tid = threadIdx.x, lane = tid & 63, wid = tid >> 6;
  if (tid < 256) {
    int r = m0 + tid; if (r > cnt - 1) r = cnt - 1;
    tok[tid] = btok[off + r];
  }
  __syncthreads();

  int posun = (lane & 7) ^ ((lane >> 3) & 7);
  int rl0 = wid * 32 + ((lane >> 3) << 1) + (posun >> 2);
  int rl1 = rl0 + 16;
  int gcol = (posun & 3) * 8;
  const us* w13e = w13 + ((size_t)e << 22);
  const us* a0 = xb + (size_t)tok[rl0] * DM + gcol;
  const us* a1 = xb + (size_t)tok[rl1] * DM + gcol;
  const us* b0 = w13e + (size_t)(n0 + rl0) * DM + gcol;
  const us* b1 = w13e + (size_t)(n0 + rl1) * DM + gcol;
  int dst0 = wid * 1024, dst1 = wid * 1024 + 512;

  auto stageA = [&](int ko, int slot) {
    gload16(a0 + ko, &As[slot][dst0]);
    gload16(a1 + ko, &As[slot][dst1]);
  };
  auto stageB = [&](int ko, int slot) {
    gload16(b0 + ko, &Bs[slot][dst0]);
    gload16(b1 + ko, &Bs[slot][dst1]);
  };

  int wm = wid >> 2, wn = wid & 3;
  int fr = lane & 15, glog = lane >> 4;
  int pos = (((fr & 1) << 2) | glog) ^ ((fr >> 1) & 7);
  int aoff = (wm * 64 + (fr >> 1)) * 64 + pos * 8;
  int boff = (wn * 32 + (fr >> 1)) * 64 + pos * 8;
  f32x4 acc[8][4] = {};

  // prologue: stage tile0 (slots 0,1); make slot 0 ready (vmcnt BEFORE barrier)
  stageA(0, 0); stageB(0, 0); stageA(32, 1); stageB(32, 1);
  asm volatile("s_waitcnt vmcnt(4)" ::: "memory");
  __builtin_amdgcn_s_barrier();

  const int NK = DM / 64;
  for (int t = 0; t < NK; ++t) {
    int sl0 = (2 * t) & 3, sl1 = sl0 ^ 1;
    int kn = (t + 1 < NK) ? (t + 1) : t;
    int sn0 = (sl0 + 2) & 3, sn1 = sn0 ^ 1;
    int kb = kn * 64;
    short8 a[4], b[4];

    FFN_PHASE(sl0, 0, 1, stageA(kb, sn0), 0)
    FFN_PHASE(sl0, 4, 0, stageB(kb, sn0), 1)
    FFN_PHASE(sl1, 0, 1, stageA(kb + 32, sn1), 0)
    FFN_PHASE(sl1, 4, 0, stageB(kb + 32, sn1), 1)
  }
  asm volatile("s_waitcnt vmcnt(0)" ::: "memory");

  // epilogue: W1/W3 paired IN-REGISTER (ni even/odd), all lanes store.
  int c = lane & 15, r4 = (lane >> 4) * 4;
  int fb = (n0 + wn * 64) >> 1;
  #pragma unroll
  for (int mi = 0; mi < 8; ++mi) {
    #pragma unroll
    for (int rg = 0; rg < 4; ++rg) {
      int gr = m0 + wm * 128 + mi * 16 + r4 + rg;
      if (gr < cnt) {
        us* hrow = hg + (size_t)(off + gr) * DF;
        #pragma unroll
        for (int j = 0; j < 2; ++j) {
          float a1v = acc[mi][2 * j][rg];
          float a3v = acc[mi][2 * j + 1][rg];
          float h = (a1v / (1.f + __expf(-a1v))) * a3v;
          hrow[fb + j * 16 + c] = f2bf(h);
        }
      }
    }
  }
}

// ---------------- FFN pass 2: ys[slot] = Hg[slot] * W2^T (bf16 out) ----------------
__global__ __launch_bounds__(512, 2) void k_ffn2(
    const us* __restrict__ hg, const us* __restrict__ w2b,
    const int* __restrict__ offs, const int* __restrict__ cnts,
    us* __restrict__ ys) {
  int e = blockIdx.z;
  int cnt = cnts[e];
  int m0 = blockIdx.y * 256;
  if (m0 >= cnt) return;
  int n0 = blockIdx.x * 256;
  int off = offs[e];
  __shared__ __align__(16) short As[4][8192];
  __shared__ __align__(16) short Bs[4][8192];
  int tid = threadIdx.x, lane = tid & 63, wid = tid >> 6;

  int posun = (lane & 7) ^ ((lane >> 3) & 7);
  int rl0 = wid * 32 + ((lane >> 3) << 1) + (posun >> 2);
  int rl1 = rl0 + 16;
  int gcol = (posun & 3) * 8;
  int ar0 = m0 + rl0; if (ar0 > cnt - 1) ar0 = cnt - 1;
  int ar1 = m0 + rl1; if (ar1 > cnt - 1) ar1 = cnt - 1;
  const us* w2e = w2b + ((size_t)e << 21);
  const us* a0 = hg + (size_t)(off + ar0) * DF + gcol;
  const us* a1 = hg + (size_t)(off + ar1) * DF + gcol;
  const us* b0 = w2e + (size_t)(n0 + rl0) * DF + gcol;
  const us* b1 = w2e + (size_t)(n0 + rl1) * DF + gcol;
  int dst0 = wid * 1024, dst1 = wid * 1024 + 512;

  auto stageA = [&](int ko, int slot) {
    gload16(a0 + ko, &As[slot][dst0]);
    gload16(a1 + ko, &As[slot][dst1]);
  };
  auto stageB = [&](int ko, int slot) {
    gload16(b0 + ko, &Bs[slot][dst0]);
    gload16(b1 + ko, &Bs[slot][dst1]);
  };

  int wm = wid >> 2, wn = wid & 3;
  int fr = lane & 15, glog = lane >> 4;
  int pos = (((fr & 1) << 2) | glog) ^ ((fr >> 1) & 7);
  int aoff = (wm * 64 + (fr >> 1)) * 64 + pos * 8;
  int boff = (wn * 32 + (fr >> 1)) * 64 + pos * 8;
  f32x4 acc[8][4] = {};

  stageA(0, 0); stageB(0, 0); stageA(32, 1); stageB(32, 1);
  asm volatile("s_waitcnt vmcnt(4)" ::: "memory");
  __builtin_amdgcn_s_barrier();

  const int NK = DF / 64;
  for (int t = 0; t < NK; ++t) {
    int sl0 = (2 * t) & 3, sl1 = sl0 ^ 1;
    int kn = (t + 1 < NK) ? (t + 1) : t;
    int sn0 = (sl0 + 2) & 3, sn1 = sn0 ^ 1;
    int kb = kn * 64;
    short8 a[4], b[4];

    FFN_PHASE(sl0, 0, 1, stageA(kb, sn0), 0)
    FFN_PHASE(sl0, 4, 0, stageB(kb, sn0), 1)
    FFN_PHASE(sl1, 0, 1, stageA(kb + 32, sn1), 0)
    FFN_PHASE(sl1, 4, 0, stageB(kb + 32, sn1), 1)
  }
  asm volatile("s_waitcnt vmcnt(0)" ::: "memory");

  int c = lane & 15, r4 = (lane >> 4) * 4;
  #pragma unroll
  for (int mi = 0; mi < 8; ++mi) {
    #pragma unroll
    for (int rg = 0; rg < 4; ++rg) {
      int gr = m0 + wm * 128 + mi * 16 + r4 + rg;
      if (gr < cnt) {
        us* yrow = ys + (size_t)(off + gr) * DM + n0;
        #pragma unroll
        for (int ni = 0; ni < 4; ++ni)
          yrow[wn * 64 + ni * 16 + c] = f2bf(acc[mi][ni][rg]);
      }
    }
  }
}

// ---------------- gather: out[t] = g0*ys[pos0] + g1*ys[pos1] ----------------
__global__ void k_gather(const us* __restrict__ ys, const int* __restrict__ pos,
                         const float2* __restrict__ gts, float* __restrict__ out) {
  int idx = blockIdx.x * blockDim.x + threadIdx.x;
  int t = idx >> 8;
  int d4 = idx & 255;
  float2 g = gts[t];
  ushort4 a = ((const ushort4*)(ys + (size_t)pos[2 * t] * DM))[d4];
  ushort4 b = ((const ushort4*)(ys + (size_t)pos[2 * t + 1] * DM))[d4];
  float4 o;
  o.x = g.x * bf2f(a.x) + g.y * bf2f(b.x);
  o.y = g.x * bf2f(a.y) + g.y * bf2f(b.y);
  o.z = g.x * bf2f(a.z) + g.y * bf2f(b.z);
  o.w = g.x * bf2f(a.w) + g.y * bf2f(b.w);
  ((float4*)out)[idx] = o;
}

// ---------------- workspace layout (bytes) ----------------
// 0        : ctrl (cntb@0, cnt1@32, offs@96, imp@128, z2@160)
// 4096     : epack  int[8192]
// 36864    : gts    float2[8192]
// 102400   : btok   int[16384]
// 167936   : pos    int[16384]
// 233472   : x_bf16   (16.78 MB)
// 17010688 : W13_bf16 paired (67.11 MB)  <- ys bf16 aliases after ffn1
// 84119552 : W2_bf16  (33.55 MB)
// 117673984: Hg bf16  (67.11 MB)   -> total ~176 MiB

extern "C" void kernel_launch(void* const* d_in, const int* in_sizes, int n_in,
                              void* d_out, int out_size, void* d_ws, size_t ws_size,
                              hipStream_t stream) {
  const float* x  = (const float*)d_in[0];
  const float* wr = (const float*)d_in[1];
  const float* w1 = (const float*)d_in[2];
  const float* w3 = (const float*)d_in[3];
  const float* w2 = (const float*)d_in[4];
  float* out = (float*)d_out;

  uint8_t* ws = (uint8_t*)d_ws;
  int*    cntb   = (int*)(ws + 0);
  int*    cnt1   = (int*)(ws + 32);
  int*    offs   = (int*)(ws + 96);
  float*  imp    = (float*)(ws + 128);
  float*  z2     = (float*)(ws + 160);
  int*    epack  = (int*)(ws + 4096);
  float2* gts    = (float2*)(ws + 36864);
  int*    btok   = (int*)(ws + 102400);
  int*    pos    = (int*)(ws + 167936);
  us*     xbf    = (us*)(ws + 233472);
  us*     w13    = (us*)(ws + 17010688);
  us*     w2bf   = (us*)(ws + 84119552);
  us*     hg     = (us*)(ws + 117673984);
  us*     ysb    = (us*)(ws + 17010688);   // aliases w13 (dead after ffn1)

  hipMemsetAsync(ws, 0, 4096, stream);

  k_router<<<RT_BLOCKS, 256, 0, stream>>>(x, wr, cntb, cnt1, imp, z2, epack, gts, xbf);
  k_cvtw<<<dim3(2048, 3), 256, 0, stream>>>(
      (const float4*)w1, (const float4*)w3, (const float4*)w2,
      (ushort4*)w13, (ushort4*)w2bf);

  k_finalize<<<1, 64, 0, stream>>>(cntb, cnt1, imp, z2, offs, out + (size_t)NT * DM);
  k_scatter<<<8, 64, 0, stream>>>(epack, gts, offs, btok, pos);

  k_ffn1<<<dim3(16, 64, 8), 512, 0, stream>>>(xbf, w13, offs, cntb, btok, hg);
  k_ffn2<<<dim3(4, 64, 8), 512, 0, stream>>>(hg, w2bf, offs, cntb, ysb);
  k_gather<<<NT * DM / 4 / 256, 256, 0, stream>>>(ysb, pos, gts, out);
}

// Round 12
// 503.744 us; speedup vs baseline: 1.0938x; 1.0938x over previous
//
#include <hip/hip_runtime.h>
#include <stdint.h>

#define NT 8192      // tokens
#define DM 1024      // d_model
#define DF 2048      // d_ff
#define RT_BLOCKS 256

typedef __attribute__((ext_vector_type(8))) short short8;
typedef __attribute__((ext_vector_type(4))) float f32x4;
typedef unsigned short us;

__device__ __forceinline__ us f2bf(float f) {
  uint32_t x = __float_as_uint(f);
  return (us)((x + 0x7fffu + ((x >> 16) & 1u)) >> 16);
}
__device__ __forceinline__ float bf2f(us v) {
  return __uint_as_float(((uint32_t)v) << 16);
}

__device__ __forceinline__ void gload16(const void* g, void* l) {
  __builtin_amdgcn_global_load_lds(
      (const __attribute__((address_space(1))) uint32_t*)g,
      (__attribute__((address_space(3))) uint32_t*)l, 16, 0, 0);
}

// ---------------- weight converts: 32B loads, 16B stores ----------------
// W13 pairing layout: W1 row f -> n = 32*(f>>4) + (f&15); W3 row f -> +16.
__global__ void k_cvtw(const float4* __restrict__ w1, const float4* __restrict__ w3,
                       const float4* __restrict__ w2,
                       short8* __restrict__ w13, short8* __restrict__ w2bf) {
  int s = blockIdx.y;
  const float4* src = (s == 0) ? w1 : (s == 1) ? w3 : w2;
  int n8 = 8 * DF * DM / 8;      // 2^21 groups of 8 elems
  int i = blockIdx.x * blockDim.x + threadIdx.x;
  int st = gridDim.x * blockDim.x;
  for (; i < n8; i += st) {
    float4 va = src[2 * i], vb = src[2 * i + 1];
    short8 o;
    o[0] = (short)f2bf(va.x); o[1] = (short)f2bf(va.y);
    o[2] = (short)f2bf(va.z); o[3] = (short)f2bf(va.w);
    o[4] = (short)f2bf(vb.x); o[5] = (short)f2bf(vb.y);
    o[6] = (short)f2bf(vb.z); o[7] = (short)f2bf(vb.w);
    if (s == 2) {
      w2bf[i] = o;
    } else {
      int e = i >> 18;                 // DF*DM/8 = 2^18 per expert
      int rem = i & ((1 << 18) - 1);
      int f = rem >> 7;                // DM/8 = 128 groups per row
      int k8 = rem & 127;
      int n = 32 * (f >> 4) + 16 * s + (f & 15);
      w13[((size_t)e << 19) + (size_t)n * 128 + k8] = o;
    }
  }
}

// ---------------- router ----------------
__global__ void k_router(const float* __restrict__ x, const float* __restrict__ wr,
                         int* cntb, int* cnt1, float* imp, float* z2,
                         int* epack, float2* gts, us* __restrict__ xbf) {
  int lane = threadIdx.x & 63;
  int wid = threadIdx.x >> 6;
  const float4* w4 = (const float4*)wr;

  float imp_acc[8] = {0.f, 0.f, 0.f, 0.f, 0.f, 0.f, 0.f, 0.f};
  float z2_acc = 0.f;
  int cb_acc[8] = {0, 0, 0, 0, 0, 0, 0, 0};
  int c1_acc[8] = {0, 0, 0, 0, 0, 0, 0, 0};

  for (int t = blockIdx.x * 4 + wid; t < NT; t += RT_BLOCKS * 4) {
    const float4* x4 = (const float4*)(x + (size_t)t * DM);
    ushort4* xb4 = (ushort4*)(xbf + (size_t)t * DM);
    float4 xv[4];
    #pragma unroll
    for (int j = 0; j < 4; ++j) {
      xv[j] = x4[lane + 64 * j];
      ushort4 o;
      o.x = f2bf(xv[j].x); o.y = f2bf(xv[j].y); o.z = f2bf(xv[j].z); o.w = f2bf(xv[j].w);
      xb4[lane + 64 * j] = o;
    }
    float p[8];
    #pragma unroll
    for (int e = 0; e < 8; ++e) p[e] = 0.f;
    #pragma unroll
    for (int j = 0; j < 4; ++j) {
      #pragma unroll
      for (int e = 0; e < 8; ++e) {
        float4 wv = w4[e * 256 + lane + 64 * j];
        p[e] += xv[j].x * wv.x + xv[j].y * wv.y + xv[j].z * wv.z + xv[j].w * wv.w;
      }
    }
    #pragma unroll
    for (int off = 32; off > 0; off >>= 1) {
      #pragma unroll
      for (int e = 0; e < 8; ++e) p[e] += __shfl_down(p[e], off);
    }
    if (lane == 0) {
      float m = p[0];
      #pragma unroll
      for (int e = 1; e < 8; ++e) m = fmaxf(m, p[e]);
      float pr[8], sum = 0.f;
      #pragma unroll
      for (int e = 0; e < 8; ++e) { pr[e] = expf(p[e] - m); sum += pr[e]; }
      float inv = 1.f / sum;
      #pragma unroll
      for (int e = 0; e < 8; ++e) pr[e] *= inv;
      float z = m + logf(sum);
      int e0 = 0; float b0 = p[0];
      #pragma unroll
      for (int e = 1; e < 8; ++e) { if (p[e] > b0) { b0 = p[e]; e0 = e; } }
      int e1 = -1; float b1 = -1e30f;
      #pragma unroll
      for (int e = 0; e < 8; ++e) { if (e != e0 && p[e] > b1) { b1 = p[e]; e1 = e; } }
      float p0 = 0.f, p1 = 0.f;
      #pragma unroll
      for (int e = 0; e < 8; ++e) {
        p0 = (e == e0) ? pr[e] : p0;
        p1 = (e == e1) ? pr[e] : p1;
      }
      float gs = p0 + p1 + 1e-9f;
      epack[t] = e0 | (e1 << 16);
      gts[t] = make_float2(p0 / gs, p1 / gs);
      z2_acc += z * z;
      #pragma unroll
      for (int e = 0; e < 8; ++e) {
        imp_acc[e] += pr[e];
        cb_acc[e] += (e == e0) + (e == e1);
        c1_acc[e] += (e == e0);
      }
    }
  }

  __shared__ float simp[4][8];
  __shared__ float sz2[4];
  __shared__ int scb[4][8];
  __shared__ int sc1[4][8];
  if (lane == 0) {
    #pragma unroll
    for (int e = 0; e < 8; ++e) { simp[wid][e] = imp_acc[e]; scb[wid][e] = cb_acc[e]; sc1[wid][e] = c1_acc[e]; }
    sz2[wid] = z2_acc;
  }
  __syncthreads();
  int tid = threadIdx.x;
  if (tid < 8) {
    float ss = simp[0][tid] + simp[1][tid] + simp[2][tid] + simp[3][tid];
    int b = scb[0][tid] + scb[1][tid] + scb[2][tid] + scb[3][tid];
    int o = sc1[0][tid] + sc1[1][tid] + sc1[2][tid] + sc1[3][tid];
    atomicAdd(&imp[tid], ss);
    atomicAdd(&cntb[tid], b);
    atomicAdd(&cnt1[tid], o);
  } else if (tid == 8) {
    atomicAdd(z2, sz2[0] + sz2[1] + sz2[2] + sz2[3]);
  }
}

// ---------------- offsets + scalar losses ----------------
__global__ void k_finalize(const int* cntb, const int* cnt1, const float* imp,
                           const float* z2, int* offs, float* otail) {
  if (threadIdx.x == 0 && blockIdx.x == 0) {
    int o = 0;
    for (int e = 0; e < 8; ++e) { offs[e] = o; o += cntb[e]; }
    otail[0] = 1e-3f * z2[0] / (float)NT;
    float aux = 0.f;
    for (int e = 0; e < 8; ++e)
      aux += (imp[e] / (float)NT) * ((float)cnt1[e] / (float)NT);
    otail[1] = aux * 8.f;
  }
}

// ---------------- deterministic stable scatter ----------------
__global__ void k_scatter(const int* __restrict__ epack, const float2* __restrict__ gts,
                          const int* __restrict__ offs,
                          int* __restrict__ btok, int* __restrict__ pos) {
  int e = blockIdx.x;
  int lane = threadIdx.x;
  int base = offs[e];
  int run = 0;
  for (int j0 = 0; j0 < 2 * NT; j0 += 64) {
    int j = j0 + lane;
    int t = j >> 1;
    int ep = epack[t];
    int sel = (j & 1) ? (ep >> 16) : (ep & 0xffff);
    bool f = (sel == e);
    unsigned long long m = __ballot(f);
    int rank = __popcll(m & ((1ull << lane) - 1ull));
    if (f) {
      int slot = base + run + rank;
      btok[slot] = t;
      pos[j] = slot;
    }
    run += __popcll(m);
  }
}

// ============================================================================
// m97-structure grouped GEMM: 128x128 tile, BK=64 (2 half-K slots of 32 cols),
// 256 thr (4 waves 2Mx2N, wave 64x64), SINGLE-buffered 32KB LDS ->
// ~4 blocks/CU co-resident (m114 implicit overlap). Per K-tile:
// stage 8 gload_lds -> syncthreads -> 2x(ds_read frags + 16 MFMA) -> syncthreads.
// Slot layout (verified 0-conflict): 64 prows x 64 shorts; logical (row,g):
// prow=row>>1, pos=(((row&1)<<2)|g)^(prow&7), cell=prow*64+pos*8.
// Staging: thread tid -> cells {tid, tid+256}: prow=tid>>3(+32), pos=tid&7;
// source row = prow*2 + (pu>>2), col = (pu&3)*8, pu = (tid&7)^(prow&7).
// (+32 preserves prow&7 -> second cell = same row+64, same col.)
// ============================================================================

// ---------------- FFN pass 1: Hg = silu(Xg*W1^T)*(Xg*W3^T), W13 paired ----------------
__global__ __launch_bounds__(256) void k_ffn1(
    const us* __restrict__ xb, const us* __restrict__ w13,
    const int* __restrict__ offs, const int* __restrict__ cnts,
    const int* __restrict__ btok, us* __restrict__ hg) {
  int e = blockIdx.z;
  int cnt = cnts[e];
  int m0 = blockIdx.y * 128;
  if (m0 >= cnt) return;
  int n0 = blockIdx.x * 128;           // over paired N = 4096
  int off = offs[e];
  __shared__ __align__(16) short As[2][4096];
  __shared__ __align__(16) short Bs[2][4096];
  __shared__ int tok[128];
  int tid = threadIdx.x, lane = tid & 63, wid = tid >> 6;
  if (tid < 128) {
    int r = m0 + tid; if (r > cnt - 1) r = cnt - 1;
    tok[tid] = btok[off + r];
  }
  __syncthreads();

  // staging sources
  int prow = tid >> 3;                 // 0..31
  int pu = (tid & 7) ^ (prow & 7);
  int row0 = prow * 2 + (pu >> 2);     // 0..63 (cell2 = row0+64)
  int gc = (pu & 3) * 8;
  const us* w13e = w13 + ((size_t)e << 22);
  const us* a0 = xb + (size_t)tok[row0] * DM + gc;
  const us* a1 = xb + (size_t)tok[row0 + 64] * DM + gc;
  const us* b0 = w13e + (size_t)(n0 + row0) * DM + gc;
  const us* b1 = w13e + (size_t)(n0 + row0 + 64) * DM + gc;
  int dsl = tid * 8;

  // fragment read offsets
  int wm = wid >> 1, wn = wid & 1;
  int fr = lane & 15, glog = lane >> 4;
  int pos = (((fr & 1) << 2) | glog) ^ ((fr >> 1) & 7);
  int aoff = (wm * 32 + (fr >> 1)) * 64 + pos * 8;
  int boff = (wn * 32 + (fr >> 1)) * 64 + pos * 8;
  f32x4 acc[4][4] = {};

  const int NK = DM / 64;
  for (int kt = 0; kt < NK; ++kt) {
    int k0 = kt * 64;
    #pragma unroll
    for (int h = 0; h < 2; ++h) {
      int ko = k0 + h * 32;
      gload16(a0 + ko, &As[h][dsl]);
      gload16(a1 + ko, &As[h][dsl + 2048]);
      gload16(b0 + ko, &Bs[h][dsl]);
      gload16(b1 + ko, &Bs[h][dsl + 2048]);
    }
    __syncthreads();
    #pragma unroll
    for (int h = 0; h < 2; ++h) {
      short8 a[4], b[4];
      #pragma unroll
      for (int mi = 0; mi < 4; ++mi) a[mi] = *(const short8*)&As[h][aoff + mi * 512];
      #pragma unroll
      for (int ni = 0; ni < 4; ++ni) b[ni] = *(const short8*)&Bs[h][boff + ni * 512];
      #pragma unroll
      for (int mi = 0; mi < 4; ++mi) {
        #pragma unroll
        for (int ni = 0; ni < 4; ++ni)
          acc[mi][ni] = __builtin_amdgcn_mfma_f32_16x16x32_bf16(a[mi], b[ni], acc[mi][ni], 0, 0, 0);
      }
    }
    __syncthreads();
  }

  // epilogue: W1/W3 paired in-register (ni even/odd), all lanes store
  int c = lane & 15, r4 = (lane >> 4) * 4;
  int fb = (n0 + wn * 64) >> 1;
  #pragma unroll
  for (int mi = 0; mi < 4; ++mi) {
    #pragma unroll
    for (int rg = 0; rg < 4; ++rg) {
      int gr = m0 + wm * 64 + mi * 16 + r4 + rg;
      if (gr < cnt) {
        us* hrow = hg + (size_t)(off + gr) * DF;
        #pragma unroll
        for (int j = 0; j < 2; ++j) {
          float a1v = acc[mi][2 * j][rg];
          float a3v = acc[mi][2 * j + 1][rg];
          float h = (a1v / (1.f + __expf(-a1v))) * a3v;
          hrow[fb + j * 16 + c] = f2bf(h);
        }
      }
    }
  }
}

// ---------------- FFN pass 2: ys[slot] = Hg[slot] * W2^T (bf16 out) ----------------
__global__ __launch_bounds__(256) void k_ffn2(
    const us* __restrict__ hg, const us* __restrict__ w2b,
    const int* __restrict__ offs, const int* __restrict__ cnts,
    us* __restrict__ ys) {
  int e = blockIdx.z;
  int cnt = cnts[e];
  int m0 = blockIdx.y * 128;
  if (m0 >= cnt) return;
  int n0 = blockIdx.x * 128;           // over DM = 1024
  int off = offs[e];
  __shared__ __align__(16) short As[2][4096];
  __shared__ __align__(16) short Bs[2][4096];
  int tid = threadIdx.x, lane = tid & 63, wid = tid >> 6;

  int prow = tid >> 3;
  int pu = (tid & 7) ^ (prow & 7);
  int row0 = prow * 2 + (pu >> 2);
  int gc = (pu & 3) * 8;
  int ar0 = m0 + row0;      if (ar0 > cnt - 1) ar0 = cnt - 1;
  int ar1 = m0 + row0 + 64; if (ar1 > cnt - 1) ar1 = cnt - 1;
  const us* w2e = w2b + ((size_t)e << 21);
  const us* a0 = hg + (size_t)(off + ar0) * DF + gc;
  const us* a1 = hg + (size_t)(off + ar1) * DF + gc;
  const us* b0 = w2e + (size_t)(n0 + row0) * DF + gc;
  const us* b1 = w2e + (size_t)(n0 + row0 + 64) * DF + gc;
  int dsl = tid * 8;

  int wm = wid >> 1, wn = wid & 1;
  int fr = lane & 15, glog = lane >> 4;
  int pos = (((fr & 1) << 2) | glog) ^ ((fr >> 1) & 7);
  int aoff = (wm * 32 + (fr >> 1)) * 64 + pos * 8;
  int boff = (wn * 32 + (fr >> 1)) * 64 + pos * 8;
  f32x4 acc[4][4] = {};

  const int NK = DF / 64;
  for (int kt = 0; kt < NK; ++kt) {
    int k0 = kt * 64;
    #pragma unroll
    for (int h = 0; h < 2; ++h) {
      int ko = k0 + h * 32;
      gload16(a0 + ko, &As[h][dsl]);
      gload16(a1 + ko, &As[h][dsl + 2048]);
      gload16(b0 + ko, &Bs[h][dsl]);
      gload16(b1 + ko, &Bs[h][dsl + 2048]);
    }
    __syncthreads();
    #pragma unroll
    for (int h = 0; h < 2; ++h) {
      short8 a[4], b[4];
      #pragma unroll
      for (int mi = 0; mi < 4; ++mi) a[mi] = *(const short8*)&As[h][aoff + mi * 512];
      #pragma unroll
      for (int ni = 0; ni < 4; ++ni) b[ni] = *(const short8*)&Bs[h][boff + ni * 512];
      #pragma unroll
      for (int mi = 0; mi < 4; ++mi) {
        #pragma unroll
        for (int ni = 0; ni < 4; ++ni)
          acc[mi][ni] = __builtin_amdgcn_mfma_f32_16x16x32_bf16(a[mi], b[ni], acc[mi][ni], 0, 0, 0);
      }
    }
    __syncthreads();
  }

  int c = lane & 15, r4 = (lane >> 4) * 4;
  #pragma unroll
  for (int mi = 0; mi < 4; ++mi) {
    #pragma unroll
    for (int rg = 0; rg < 4; ++rg) {
      int gr = m0 + wm * 64 + mi * 16 + r4 + rg;
      if (gr < cnt) {
        us* yrow = ys + (size_t)(off + gr) * DM + n0;
        #pragma unroll
        for (int ni = 0; ni < 4; ++ni)
          yrow[wn * 64 + ni * 16 + c] = f2bf(acc[mi][ni][rg]);
      }
    }
  }
}

// ---------------- gather: out[t] = g0*ys[pos0] + g1*ys[pos1] ----------------
__global__ void k_gather(const us* __restrict__ ys, const int* __restrict__ pos,
                         const float2* __restrict__ gts, float* __restrict__ out) {
  int idx = blockIdx.x * blockDim.x + threadIdx.x;
  int t = idx >> 8;
  int d4 = idx & 255;
  float2 g = gts[t];
  ushort4 a = ((const ushort4*)(ys + (size_t)pos[2 * t] * DM))[d4];
  ushort4 b = ((const ushort4*)(ys + (size_t)pos[2 * t + 1] * DM))[d4];
  float4 o;
  o.x = g.x * bf2f(a.x) + g.y * bf2f(b.x);
  o.y = g.x * bf2f(a.y) + g.y * bf2f(b.y);
  o.z = g.x * bf2f(a.z) + g.y * bf2f(b.z);
  o.w = g.x * bf2f(a.w) + g.y * bf2f(b.w);
  ((float4*)out)[idx] = o;
}

// ---------------- workspace layout (bytes) ----------------
// 0        : ctrl (cntb@0, cnt1@32, offs@96, imp@128, z2@160)
// 4096     : epack  int[8192]
// 36864    : gts    float2[8192]
// 102400   : btok   int[16384]
// 167936   : pos    int[16384]
// 233472   : x_bf16   (16.78 MB)
// 17010688 : W13_bf16 paired (67.11 MB)  <- ys bf16 aliases after ffn1
// 84119552 : W2_bf16  (33.55 MB)
// 117673984: Hg bf16  (67.11 MB)   -> total ~176 MiB

extern "C" void kernel_launch(void* const* d_in, const int* in_sizes, int n_in,
                              void* d_out, int out_size, void* d_ws, size_t ws_size,
                              hipStream_t stream) {
  const float* x  = (const float*)d_in[0];
  const float* wr = (const float*)d_in[1];
  const float* w1 = (const float*)d_in[2];
  const float* w3 = (const float*)d_in[3];
  const float* w2 = (const float*)d_in[4];
  float* out = (float*)d_out;

  uint8_t* ws = (uint8_t*)d_ws;
  int*    cntb   = (int*)(ws + 0);
  int*    cnt1   = (int*)(ws + 32);
  int*    offs   = (int*)(ws + 96);
  float*  imp    = (float*)(ws + 128);
  float*  z2     = (float*)(ws + 160);
  int*    epack  = (int*)(ws + 4096);
  float2* gts    = (float2*)(ws + 36864);
  int*    btok   = (int*)(ws + 102400);
  int*    pos    = (int*)(ws + 167936);
  us*     xbf    = (us*)(ws + 233472);
  us*     w13    = (us*)(ws + 17010688);
  us*     w2bf   = (us*)(ws + 84119552);
  us*     hg     = (us*)(ws + 117673984);
  us*     ysb    = (us*)(ws + 17010688);   // aliases w13 (dead after ffn1)

  hipMemsetAsync(ws, 0, 4096, stream);

  k_router<<<RT_BLOCKS, 256, 0, stream>>>(x, wr, cntb, cnt1, imp, z2, epack, gts, xbf);
  k_cvtw<<<dim3(2048, 3), 256, 0, stream>>>(
      (const float4*)w1, (const float4*)w3, (const float4*)w2,
      (short8*)w13, (short8*)w2bf);

  k_finalize<<<1, 64, 0, stream>>>(cntb, cnt1, imp, z2, offs, out + (size_t)NT * DM);
  k_scatter<<<8, 64, 0, stream>>>(epack, gts, offs, btok, pos);

  k_ffn1<<<dim3(32, 128, 8), 256, 0, stream>>>(xbf, w13, offs, cntb, btok, hg);
  k_ffn2<<<dim3(8, 128, 8), 256, 0, stream>>>(hg, w2bf, offs, cntb, ysb);
  k_gather<<<NT * DM / 4 / 256, 256, 0, stream>>>(ysb, pos, gts, out);
}